// Round 7
// baseline (221.149 us; speedup 1.0000x reference)
//
#include <hip/hip_runtime.h>
#include <math.h>

#define BB 4
#define SS 8192
#define HH 2048
#define EE 16
#define BRD_ 256
#define BSZ 1024   /* block size from _adjust(8192) */
#define NN 8       /* SS/BSZ */
#define NB 32      /* BB*NN */
#define MAXTOK 1720 /* int(8192*0.21000000000000002) */
#define HHALF 1024
#define TC 32      /* t-chunks per block for the mean phase */
#define ROWS 32    /* BSZ / TC */

typedef __attribute__((ext_vector_type(8))) short bf16x8;
typedef __attribute__((ext_vector_type(4))) float f32x4;

__device__ inline short f2bf(float f) {
  unsigned u = __builtin_bit_cast(unsigned, f);
  u += 0x7FFFu + ((u >> 16) & 1u);   // RNE
  return (short)(u >> 16);
}

// ---- inline wave-parallel flag logic (lanes 0..63 of one wave; NB=32, KBUD=1) ----
__device__ inline void wave_flags(const double* __restrict__ ent, int l,
                                  int& flag_out, int& fb_out) {
  const double THR = 0.6 * 1.1;  // 0.66000000000000003
  double e = (l < NB) ? ent[l] : -INFINITY;
  bool m1 = (l < NB) && (e > THR);
  unsigned long long m1mask = __ballot(m1);
  int th = __popcll(m1mask);
  double sel = m1 ? e : -INFINITY;
  #pragma unroll
  for (int o = 32; o; o >>= 1) sel = fmax(sel, __shfl_xor(sel, o));
  // cond = (th*1024>1720)&&(th>0)&&(1<th) <=> th>=2 ; kth = max of selected (KBUD=1)
  bool m2 = (th >= 2) ? ((l < NB) && (e > sel)) : m1;
  unsigned long long m2mask = __ballot(m2);
  int cum = __popcll(m2mask & ((2ULL << l) - 1ULL)) * BSZ;  // inclusive prefix
  bool tf = m2 && (cum <= MAXTOK);
  bool bf = (l < NB) && ((!m1) || (m2 && !tf));
  flag_out = tf ? 1 : (bf ? 2 : 0);
  unsigned long long tfmask = __ballot(tf);
  fb_out = tfmask ? (__ffsll(tfmask) - 1) : -1;
}

// ================= K1: block-mean partials + fan-in router (fused) =================
// Grid NB*TC = 1024 wgs. Each wg: fp64 partial sums for (bn,tc). Last wg per bn
// (device-scope counter) reduces partials and runs GEMM1->LN->GELU->GEMM2->entropy.
__global__ __launch_bounds__(256, 4) void k_main(const float* __restrict__ x,
    double* __restrict__ part,
    const float* __restrict__ bw1, const float* __restrict__ bb1,
    const float* __restrict__ lng, const float* __restrict__ lnb,
    const float* __restrict__ bw2, const float* __restrict__ bb2,
    double* __restrict__ ent, float* __restrict__ bwv, int* __restrict__ bwi,
    int* __restrict__ cnt) {
  __shared__ double brs[HH];       // 16 KB block mean
  __shared__ double p2[4][BRD_];   // 8 KB GEMM1 K-split partials
  __shared__ double tg[BRD_];
  __shared__ double p3[16][EE];
  __shared__ double red[4];
  __shared__ double l2[EE];
  __shared__ double bcast;
  __shared__ int lastf;
  int wg = blockIdx.x, tid = threadIdx.x;
  int bn = wg >> 5, tc = wg & 31;
  int b = bn >> 3, n = bn & 7;

  // ---- Phase A: mean partials over ROWS rows ----
  const float* base = x + ((size_t)(b * SS + n * BSZ + tc * ROWS) * HH);
  {
    double a0=0,a1=0,a2=0,a3=0,a4=0,a5=0,a6=0,a7=0;
    #pragma unroll 4
    for (int t = 0; t < ROWS; ++t) {
      const float4* r = (const float4*)(base + (size_t)t * HH);
      float4 u = r[tid];
      float4 v = r[tid + 256];
      a0 += u.x; a1 += u.y; a2 += u.z; a3 += u.w;
      a4 += v.x; a5 += v.y; a6 += v.z; a7 += v.w;
    }
    double* p = part + ((size_t)bn * TC + tc) * HH;
    int hA = tid * 4, hB = 1024 + tid * 4;
    p[hA] = a0; p[hA+1] = a1; p[hA+2] = a2; p[hA+3] = a3;
    p[hB] = a4; p[hB+1] = a5; p[hB+2] = a6; p[hB+3] = a7;
  }
  __syncthreads();   // drains vmem stores of all waves in this wg
  if (tid == 0) {
    int r = __hip_atomic_fetch_add(cnt + bn, 1, __ATOMIC_ACQ_REL,
                                   __HIP_MEMORY_SCOPE_AGENT);
    lastf = (r == TC - 1);
  }
  __syncthreads();
  if (!lastf) return;

  // ---- Phase B (last wg of bn only): reduce partials -> block mean ----
  #pragma unroll
  for (int i = 0; i < 8; ++i) {
    int h = i * 256 + tid;
    const double* pp = part + ((size_t)bn * TC) * HH + h;
    double s = 0;
    #pragma unroll
    for (int t = 0; t < TC; ++t) s += pp[(size_t)t * HH];
    brs[h] = s * (1.0 / BSZ);
  }
  __syncthreads();

  // ---- Phase C: GEMM1 [1,2048]x[2048,256], K split 4-way across waves ----
  {
    int j0 = (tid & 63) * 4, kq = tid >> 6;
    const float* wp = bw1 + (size_t)(kq * 512) * BRD_ + j0;
    const double* brk = brs + kq * 512;
    double a0=0,a1=0,a2=0,a3=0,c0=0,c1=0,c2=0,c3=0;
    #pragma unroll 8
    for (int k = 0; k < 512; k += 2) {
      float4 w0 = *(const float4*)(wp + (size_t)k * BRD_);
      float4 w1 = *(const float4*)(wp + (size_t)(k + 1) * BRD_);
      double bk0 = brk[k], bk1 = brk[k + 1];
      a0 += bk0 * w0.x; a1 += bk0 * w0.y; a2 += bk0 * w0.z; a3 += bk0 * w0.w;
      c0 += bk1 * w1.x; c1 += bk1 * w1.y; c2 += bk1 * w1.z; c3 += bk1 * w1.w;
    }
    p2[kq][j0]   = a0 + c0; p2[kq][j0+1] = a1 + c1;
    p2[kq][j0+2] = a2 + c2; p2[kq][j0+3] = a3 + c3;
  }
  __syncthreads();
  double a = (double)bb1[tid] + p2[0][tid] + p2[1][tid] + p2[2][tid] + p2[3][tid];

  // ---- LayerNorm (eps=1e-5, population var) ----
  double v = a;
  for (int o = 32; o; o >>= 1) v += __shfl_down(v, o);
  if ((tid & 63) == 0) red[tid >> 6] = v;
  __syncthreads();
  if (tid == 0) bcast = (red[0] + red[1] + red[2] + red[3]) * (1.0 / BRD_);
  __syncthreads();
  double m = bcast;
  double d = a - m;
  v = d * d;
  for (int o = 32; o; o >>= 1) v += __shfl_down(v, o);
  if ((tid & 63) == 0) red[tid >> 6] = v;
  __syncthreads();
  if (tid == 0) bcast = (red[0] + red[1] + red[2] + red[3]) * (1.0 / BRD_);
  __syncthreads();
  double var = bcast;
  double xn = d / sqrt(var + 1e-5) * (double)lng[tid] + (double)lnb[tid];
  tg[tid] = 0.5 * xn * (1.0 + erf(xn * 0.7071067811865476));  // exact GELU
  __syncthreads();

  // ---- GEMM2 [1,256]x[256,16] ----
  {
    int e = tid & 15, jc = tid >> 4;
    double s = 0;
    const float* w2 = bw2 + (size_t)(jc * 16) * EE + e;
    #pragma unroll
    for (int jj = 0; jj < 16; ++jj) s += tg[jc * 16 + jj] * (double)w2[jj * EE];
    p3[jc][e] = s;
  }
  __syncthreads();
  if (tid < EE) {
    double acc = (double)bb2[tid];
    #pragma unroll
    for (int jc = 0; jc < 16; ++jc) acc += p3[jc][tid];
    l2[tid] = acc;
  }
  __syncthreads();

  // ---- softmax / entropy / argmax on wave 0 ----
  if (tid < 64) {
    int e = tid & 15;
    double le = l2[e];
    double mx = le;
    #pragma unroll
    for (int o = 1; o < 16; o <<= 1) mx = fmax(mx, __shfl_xor(mx, o));
    double pe = exp(le - mx);
    double se = pe;
    #pragma unroll
    for (int o = 1; o < 16; o <<= 1) se += __shfl_xor(se, o);
    double pr = pe / se;
    double q = pr + 1e-10;
    double term = -q * log(q);
    double es = term;
    #pragma unroll
    for (int o = 1; o < 16; o <<= 1) es += __shfl_xor(es, o);
    double mp = pr;
    #pragma unroll
    for (int o = 1; o < 16; o <<= 1) mp = fmax(mp, __shfl_xor(mp, o));
    unsigned long long eqm = __ballot((tid < 16) && (pr == mp));
    if (tid == 0) {
      ent[bn] = es / log(16.0);
      bwv[bn] = (float)mp;
      bwi[bn] = __ffsll(eqm) - 1;
    }
  }
}

// ================= K2: fill + token-MFMA + fan-in tail (fused) =================
// Grid 512. bid<256: fill path. bid>=256: token GEMM path (skips when fb<0).
// Every wg increments cnt2; the last (==511) runs token-softmax + aux tail.
__global__ __launch_bounds__(256) void k_out2(const double* __restrict__ ent,
    const float* __restrict__ bwv, const int* __restrict__ bwi,
    const float* __restrict__ x, const float* __restrict__ tw1, const float* __restrict__ tb1,
    const float* __restrict__ tw2, const float* __restrict__ tb2,
    float* __restrict__ routing, float* __restrict__ lpart,
    float* __restrict__ outaux, int* __restrict__ cnt2) {
  __shared__ int flg_s[NB + 1];
  __shared__ short xs_bf[64][72];
  __shared__ short wsT[64][72];
  __shared__ float ths[64][65];
  __shared__ double up[4][EE];
  __shared__ double us[EE];
  __shared__ int lastf;
  int tid = threadIdx.x;
  int bid = blockIdx.x;
  if (tid < 64) {
    int f, fb;
    wave_flags(ent, tid, f, fb);
    if (tid < NB) flg_s[tid] = f;
    if (tid == 0) flg_s[NB] = fb;
  }
  __syncthreads();
  int fb = flg_s[NB];

  if (bid < 256) {   // ---- fill path: wg = (bn, seg) ----
    int bn = bid >> 3, seg = bid & 7;
    int fl = flg_s[bn];
    if (fl != 1) {   // token path writes fl==1 rows
      int b = bn >> 3, n = bn & 7;
      float4 z = make_float4(0.f, 0.f, 0.f, 0.f);
      float4 val = z;
      int c_hit = -1;
      if (fl == 2) {
        int ai = bwi[bn];
        c_hit = ai >> 2;
        ((float*)&val)[ai & 3] = bwv[bn];
      }
      float4* out = (float4*)(routing + ((size_t)(b * SS + n * BSZ + seg * 128) * EE));
      #pragma unroll
      for (int l = 0; l < 2; ++l) {
        int idx = l * 256 + tid;
        int c = idx & 3;
        out[idx] = (c == c_hit) ? val : z;
      }
    }
  } else if (fb >= 0) {   // ---- token GEMM path (bf16 MFMA) ----
    int b = fb >> 3, n = fb & 7;
    int tb = bid - 256;
    int tg = tb >> 4, nc = tb & 15;
    int t0 = tg * 64, j0 = nc * 64;
    const float* xb = x + ((size_t)(b * SS + n * BSZ + t0) * HH);
    int wv = tid >> 6, lane = tid & 63;
    int wm = (wv >> 1) * 32, wn = (wv & 1) * 32;
    int fr = lane & 15, kg = lane >> 4;
    f32x4 acc00 = {0,0,0,0}, acc01 = {0,0,0,0}, acc10 = {0,0,0,0}, acc11 = {0,0,0,0};
    for (int k0 = 0; k0 < HH; k0 += 64) {
      #pragma unroll
      for (int i = 0; i < 16; ++i) {
        int e = i * 256 + tid; int r = e >> 6, c = e & 63;
        xs_bf[r][c] = f2bf(xb[(size_t)r * HH + k0 + c]);
      }
      #pragma unroll
      for (int i = 0; i < 16; ++i) {
        int e = i * 256 + tid; int r = e >> 6, c = e & 63;
        wsT[c][r] = f2bf(tw1[(size_t)(k0 + r) * HHALF + j0 + c]);
      }
      __syncthreads();
      #pragma unroll
      for (int kc = 0; kc < 64; kc += 32) {
        int ks = kc + kg * 8;
        bf16x8 a0 = *(const bf16x8*)&xs_bf[wm + fr][ks];
        bf16x8 a1 = *(const bf16x8*)&xs_bf[wm + 16 + fr][ks];
        bf16x8 b0 = *(const bf16x8*)&wsT[wn + fr][ks];
        bf16x8 b1 = *(const bf16x8*)&wsT[wn + 16 + fr][ks];
        acc00 = __builtin_amdgcn_mfma_f32_16x16x32_bf16(a0, b0, acc00, 0, 0, 0);
        acc01 = __builtin_amdgcn_mfma_f32_16x16x32_bf16(a0, b1, acc01, 0, 0, 0);
        acc10 = __builtin_amdgcn_mfma_f32_16x16x32_bf16(a1, b0, acc10, 0, 0, 0);
        acc11 = __builtin_amdgcn_mfma_f32_16x16x32_bf16(a1, b1, acc11, 0, 0, 0);
      }
      __syncthreads();
    }
    #pragma unroll
    for (int r = 0; r < 4; ++r) {
      int row0 = wm + kg * 4 + r, row1 = wm + 16 + kg * 4 + r;
      int col0 = wn + fr,         col1 = wn + 16 + fr;
      float v00 = acc00[r] + tb1[j0 + col0];
      float v01 = acc01[r] + tb1[j0 + col1];
      float v10 = acc10[r] + tb1[j0 + col0];
      float v11 = acc11[r] + tb1[j0 + col1];
      ths[row0][col0] = 0.5f * v00 * (1.0f + erff(v00 * 0.70710678f));
      ths[row0][col1] = 0.5f * v01 * (1.0f + erff(v01 * 0.70710678f));
      ths[row1][col0] = 0.5f * v10 * (1.0f + erff(v10 * 0.70710678f));
      ths[row1][col1] = 0.5f * v11 * (1.0f + erff(v11 * 0.70710678f));
    }
    __syncthreads();
    float* lp = lpart + (size_t)nc * (BSZ * EE);
    #pragma unroll
    for (int l = 0; l < 4; ++l) {
      int idx = l * 256 + tid; int t = idx >> 4, e = idx & 15;
      float s = 0;
      #pragma unroll
      for (int jj = 0; jj < 64; ++jj) s += ths[t][jj] * tw2[(size_t)(j0 + jj) * EE + e];
      lp[(t0 + t) * EE + e] = s;
    }
  }

  // ---- fan-in: last wg runs the tail ----
  __syncthreads();   // drain vmem stores of all waves
  if (tid == 0) {
    int r = __hip_atomic_fetch_add(cnt2, 1, __ATOMIC_ACQ_REL,
                                   __HIP_MEMORY_SCOPE_AGENT);
    lastf = (r == 511);
  }
  __syncthreads();
  if (!lastf) return;

  double us_p[EE];
  #pragma unroll
  for (int e = 0; e < EE; ++e) us_p[e] = 0;
  if (fb >= 0) {
    int b = fb >> 3, n = fb & 7;
    for (int rep = 0; rep < 4; ++rep) {
      int t = rep * 256 + tid;
      float l[EE];
      #pragma unroll
      for (int e = 0; e < EE; ++e) {
        float s = tb2[e];
        #pragma unroll
        for (int nc = 0; nc < 16; ++nc) s += lpart[(size_t)nc * (BSZ * EE) + t * EE + e];
        l[e] = s;
      }
      float mx = l[0];
      for (int e = 1; e < EE; ++e) mx = fmaxf(mx, l[e]);
      float se = 0;
      for (int e = 0; e < EE; ++e) { l[e] = expf(l[e] - mx); se += l[e]; }
      float inv = 1.0f / se;
      for (int e = 0; e < EE; ++e) l[e] *= inv;
      float4* orow = (float4*)(routing + ((size_t)(b * SS + n * BSZ + t) * EE));
      orow[0] = make_float4(l[0], l[1], l[2], l[3]);
      orow[1] = make_float4(l[4], l[5], l[6], l[7]);
      orow[2] = make_float4(l[8], l[9], l[10], l[11]);
      orow[3] = make_float4(l[12], l[13], l[14], l[15]);
      #pragma unroll
      for (int e = 0; e < EE; ++e) us_p[e] += (double)l[e];
    }
  }
  // reduce usage across 256 threads
  int w = tid >> 6;
  #pragma unroll
  for (int e = 0; e < EE; ++e) {
    double v = us_p[e];
    for (int o = 32; o; o >>= 1) v += __shfl_down(v, o);
    if ((tid & 63) == 0) up[w][e] = v;
  }
  __syncthreads();
  if (tid < EE) {
    double s = 0;
    if (fb >= 0) for (int ww = 0; ww < 4; ++ww) s += up[ww][tid];
    for (int i = 0; i < NB; ++i)
      if (flg_s[i] == 2 && bwi[i] == tid) s += (double)BSZ * (double)bwv[i];
    us[tid] = s;
  }
  __syncthreads();
  if (tid == 0) {
    double aux = 0;
    const double target = 1.0 / EE;
    for (int e = 0; e < EE; ++e) {
      double u = us[e] / (double)(BB * SS);
      aux += target * log(target / (u + 1e-10));
    }
    *outaux = (float)aux;
  }
}

extern "C" void kernel_launch(void* const* d_in, const int* in_sizes, int n_in,
                              void* d_out, int out_size, void* d_ws, size_t ws_size,
                              hipStream_t stream) {
  const float* x   = (const float*)d_in[0];
  const float* bw1 = (const float*)d_in[1];
  const float* bb1 = (const float*)d_in[2];
  const float* lng = (const float*)d_in[3];
  const float* lnb = (const float*)d_in[4];
  const float* bw2 = (const float*)d_in[5];
  const float* bb2 = (const float*)d_in[6];
  const float* tw1 = (const float*)d_in[7];
  const float* tb1 = (const float*)d_in[8];
  const float* tw2 = (const float*)d_in[9];
  const float* tb2 = (const float*)d_in[10];
  float* routing = (float*)d_out;
  float* outaux = routing + (size_t)BB * SS * EE;

  char* w = (char*)d_ws;
  size_t off = 0;
  double* part  = (double*)(w + off); off += (size_t)NB * TC * HH * 8;   // 16.8 MB
  float*  lpart = (float*) (w + off); off += 16 * (size_t)BSZ * EE * 4;  // 1 MB
  double* ent   = (double*)(w + off); off += NB * 8;
  float*  bwv   = (float*) (w + off); off += 256;
  int*    bwi   = (int*)   (w + off); off += 256;
  int*    cnt   = (int*)   (w + off); off += 256;   // cnt[0..NB-1], cnt2 = cnt+NB

  hipMemsetAsync(cnt, 0, 256, stream);
  hipLaunchKernelGGL(k_main, dim3(NB * TC), dim3(256), 0, stream, x, part,
                     bw1, bb1, lng, lnb, bw2, bb2, ent, bwv, bwi, cnt);
  hipLaunchKernelGGL(k_out2, dim3(512),     dim3(256), 0, stream, ent, bwv, bwi,
                     x, tw1, tb1, tw2, tb2, routing, lpart, outaux, cnt + NB);
}

// Round 8
// 102.108 us; speedup vs baseline: 2.1658x; 2.1658x over previous
//
#include <hip/hip_runtime.h>
#include <math.h>

#define BB 4
#define SS 8192
#define HH 2048
#define EE 16
#define BRD_ 256
#define BSZ 1024   /* block size from _adjust(8192) */
#define NN 8       /* SS/BSZ */
#define NB 32      /* BB*NN */
#define MAXTOK 1720 /* int(8192*0.21000000000000002) */
#define HHALF 1024
#define TC 16      /* t-chunks per block for the mean kernel */
#define ROWS 64    /* BSZ / TC */
#define KSP 64     /* k-slices for GEMM1 */
#define KL 32      /* HH / KSP */
#define JT 4       /* j-slices */
#define JL 64      /* BRD_ / JT */

typedef __attribute__((ext_vector_type(8))) short bf16x8;
typedef __attribute__((ext_vector_type(4))) float f32x4;

__device__ inline short f2bf(float f) {
  unsigned u = __builtin_bit_cast(unsigned, f);
  u += 0x7FFFu + ((u >> 16) & 1u);   // RNE
  return (short)(u >> 16);
}

// ---- inline wave-parallel flag logic (lanes 0..63 of one wave; NB=32, KBUD=1) ----
__device__ inline void wave_flags(const double* __restrict__ ent, int l,
                                  int& flag_out, int& fb_out) {
  const double THR = 0.6 * 1.1;  // 0.66000000000000003
  double e = (l < NB) ? ent[l] : -INFINITY;
  bool m1 = (l < NB) && (e > THR);
  unsigned long long m1mask = __ballot(m1);
  int th = __popcll(m1mask);
  double sel = m1 ? e : -INFINITY;
  #pragma unroll
  for (int o = 32; o; o >>= 1) sel = fmax(sel, __shfl_xor(sel, o));
  // cond = (th*1024>1720)&&(th>0)&&(1<th) <=> th>=2 ; kth = max of selected (KBUD=1)
  bool m2 = (th >= 2) ? ((l < NB) && (e > sel)) : m1;
  unsigned long long m2mask = __ballot(m2);
  int cum = __popcll(m2mask & ((2ULL << l) - 1ULL)) * BSZ;  // inclusive prefix
  bool tf = m2 && (cum <= MAXTOK);
  bool bf = (l < NB) && ((!m1) || (m2 && !tf));
  flag_out = tf ? 1 : (bf ? 2 : 0);
  unsigned long long tfmask = __ballot(tf);
  fb_out = tfmask ? (__ffsll(tfmask) - 1) : -1;
}

// ---------------- K1: block mean partial sums (memory-bound floor) ----------------
__global__ __launch_bounds__(256) void k_bmean(const float* __restrict__ x,
                                               double* __restrict__ part) {
  int wg = blockIdx.x;          // NB*TC = 512 wgs
  int bn = wg >> 4, tc = wg & 15;
  int b = bn >> 3, n = bn & 7;
  int tid = threadIdx.x;
  const float* base = x + ((size_t)(b * SS + n * BSZ + tc * ROWS) * HH);
  double a0=0,a1=0,a2=0,a3=0,a4=0,a5=0,a6=0,a7=0;
  #pragma unroll 8
  for (int t = 0; t < ROWS; ++t) {
    const float4* r = (const float4*)(base + (size_t)t * HH);
    float4 u = r[tid];        // h = tid*4 .. +3
    float4 v = r[tid + 256];  // h = 1024 + tid*4 .. +3
    a0 += u.x; a1 += u.y; a2 += u.z; a3 += u.w;
    a4 += v.x; a5 += v.y; a6 += v.z; a7 += v.w;
  }
  double* p = part + ((size_t)bn * TC + tc) * HH;
  int hA = tid * 4, hB = 1024 + tid * 4;
  p[hA] = a0; p[hA+1] = a1; p[hA+2] = a2; p[hA+3] = a3;
  p[hB] = a4; p[hB+1] = a5; p[hB+2] = a6; p[hB+3] = a7;
}

// ---------------- K2: reduce+GEMM1, 256 wgs = 64 k-slices x 4 j-slices ----------------
__global__ __launch_bounds__(256) void k_g1(const double* __restrict__ part,
    const float* __restrict__ bw1, double* __restrict__ g1part) {
  __shared__ double brs[NB][KL];  // 8 KB block means, this k-slice
  __shared__ float  wsm[KL][JL];  // 8 KB bw1 slice
  int bid = blockIdx.x;
  int kq = bid >> 2, jt = bid & 3;
  int k0 = kq * KL, j0 = jt * JL;
  int tid = threadIdx.x;
  // stage block means: 1024 elems (32 bn x 32 k), 4/thread, 16 indep loads each
  #pragma unroll
  for (int i = 0; i < 4; ++i) {
    int e = i * 256 + tid;
    int bn = e >> 5, k = e & 31;
    const double* pp = part + ((size_t)bn * TC) * HH + k0 + k;
    double s = 0;
    #pragma unroll
    for (int tc = 0; tc < TC; ++tc) s += pp[(size_t)tc * HH];
    brs[bn][k] = s * (1.0 / BSZ);
  }
  // stage bw1 slice: 2048 floats = 512 float4, 2/thread
  #pragma unroll
  for (int i = 0; i < 2; ++i) {
    int f = i * 256 + tid;
    int r = f >> 4, c4 = f & 15;
    float4 v = *(const float4*)(bw1 + (size_t)(k0 + r) * BRD_ + j0 + c4 * 4);
    *(float4*)&wsm[r][c4 * 4] = v;
  }
  __syncthreads();
  // compute: thread = (j, bn-octet): 8 fp64 accumulators
  int j = tid & 63;
  int bh = (tid >> 6) * 8;
  double acc[8];
  #pragma unroll
  for (int r = 0; r < 8; ++r) acc[r] = 0;
  #pragma unroll
  for (int k = 0; k < KL; ++k) {
    double wv = (double)wsm[k][j];           // conflict-free
    #pragma unroll
    for (int r = 0; r < 8; ++r) acc[r] += brs[bh + r][k] * wv;  // broadcast
  }
  #pragma unroll
  for (int r = 0; r < 8; ++r)
    g1part[((size_t)kq * NB + bh + r) * BRD_ + j0 + j] = acc[r];
}

// ---------------- K3: per-block LN -> GELU -> GEMM2 -> softmax/entropy/argmax ----------------
__global__ __launch_bounds__(256) void k_router2(const double* __restrict__ g1part,
    const float* __restrict__ bb1, const float* __restrict__ lng, const float* __restrict__ lnb,
    const float* __restrict__ bw2, const float* __restrict__ bb2,
    double* __restrict__ ent, float* __restrict__ bwv, int* __restrict__ bwi) {
  __shared__ double tg[BRD_];
  __shared__ double p3[16][EE];
  __shared__ double red[4];
  __shared__ double l2[EE];
  __shared__ double bcast;
  int bn = blockIdx.x, tid = threadIdx.x;

  double a = (double)bb1[tid];
  #pragma unroll
  for (int kq = 0; kq < KSP; ++kq) a += g1part[((size_t)kq * NB + bn) * BRD_ + tid];

  double v = a;
  for (int o = 32; o; o >>= 1) v += __shfl_down(v, o);
  if ((tid & 63) == 0) red[tid >> 6] = v;
  __syncthreads();
  if (tid == 0) bcast = (red[0] + red[1] + red[2] + red[3]) * (1.0 / BRD_);
  __syncthreads();
  double m = bcast;
  double d = a - m;
  v = d * d;
  for (int o = 32; o; o >>= 1) v += __shfl_down(v, o);
  if ((tid & 63) == 0) red[tid >> 6] = v;
  __syncthreads();
  if (tid == 0) bcast = (red[0] + red[1] + red[2] + red[3]) * (1.0 / BRD_);
  __syncthreads();
  double var = bcast;
  double xn = d / sqrt(var + 1e-5) * (double)lng[tid] + (double)lnb[tid];
  tg[tid] = 0.5 * xn * (1.0 + erf(xn * 0.7071067811865476));  // exact GELU
  __syncthreads();

  {
    int e = tid & 15, jc = tid >> 4;
    double s = 0;
    const float* w2 = bw2 + (size_t)(jc * 16) * EE + e;
    #pragma unroll
    for (int jj = 0; jj < 16; ++jj) s += tg[jc * 16 + jj] * (double)w2[jj * EE];
    p3[jc][e] = s;
  }
  __syncthreads();
  if (tid < EE) {
    double acc = (double)bb2[tid];
    #pragma unroll
    for (int jc = 0; jc < 16; ++jc) acc += p3[jc][tid];
    l2[tid] = acc;
  }
  __syncthreads();

  if (tid < 64) {
    int e = tid & 15;
    double le = l2[e];
    double mx = le;
    #pragma unroll
    for (int o = 1; o < 16; o <<= 1) mx = fmax(mx, __shfl_xor(mx, o));
    double pe = exp(le - mx);
    double se = pe;
    #pragma unroll
    for (int o = 1; o < 16; o <<= 1) se += __shfl_xor(se, o);
    double pr = pe / se;
    double q = pr + 1e-10;
    double term = -q * log(q);
    double es = term;
    #pragma unroll
    for (int o = 1; o < 16; o <<= 1) es += __shfl_xor(es, o);
    double mp = pr;
    #pragma unroll
    for (int o = 1; o < 16; o <<= 1) mp = fmax(mp, __shfl_xor(mp, o));
    unsigned long long eqm = __ballot((tid < 16) && (pr == mp));
    if (tid == 0) {
      ent[bn] = es / log(16.0);
      bwv[bn] = (float)mp;
      bwi[bn] = __ffsll(eqm) - 1;
    }
  }
}

// ---------------- K4: merged fill + MFMA token-GEMM (512 wgs; flags inline) ----------------
__global__ __launch_bounds__(256) void k_out(const double* __restrict__ ent,
    const float* __restrict__ bwv, const int* __restrict__ bwi,
    const float* __restrict__ x, const float* __restrict__ tw1, const float* __restrict__ tb1,
    const float* __restrict__ tw2, float* __restrict__ routing, float* __restrict__ lpart) {
  __shared__ int flg_s[NB + 1];
  __shared__ short xs_bf[64][72];   // stride 144B (2-way free)
  __shared__ short wsT[64][72];     // transposed tw1 slice: wsT[col][k]
  __shared__ float ths[64][65];     // gelu output
  int tid = threadIdx.x;
  int bid = blockIdx.x;
  if (tid < 64) {
    int f, fb;
    wave_flags(ent, tid, f, fb);
    if (tid < NB) flg_s[tid] = f;
    if (tid == 0) flg_s[NB] = fb;
  }
  __syncthreads();

  if (bid < 256) {   // ---- fill path: wg = (bn, seg) ----
    int bn = bid >> 3, seg = bid & 7;
    int fl = flg_s[bn];
    if (fl == 1) return;  // token path writes these rows
    int b = bn >> 3, n = bn & 7;
    float4 z = make_float4(0.f, 0.f, 0.f, 0.f);
    float4 val = z;
    int c_hit = -1;
    if (fl == 2) {
      int ai = bwi[bn];
      c_hit = ai >> 2;
      ((float*)&val)[ai & 3] = bwv[bn];
    }
    float4* out = (float4*)(routing + ((size_t)(b * SS + n * BSZ + seg * 128) * EE));
    #pragma unroll
    for (int l = 0; l < 2; ++l) {
      int idx = l * 256 + tid;
      int c = idx & 3;
      out[idx] = (c == c_hit) ? val : z;
    }
    return;
  }

  // ---- token GEMM path (bf16 MFMA): wg = (tg, nc): 64 tokens x 64 cols, K=2048 ----
  int fb = flg_s[NB];
  if (fb < 0) return;
  int b = fb >> 3, n = fb & 7;
  int tb = bid - 256;
  int tg = tb >> 4, nc = tb & 15;
  int t0 = tg * 64, j0 = nc * 64;
  const float* xb = x + ((size_t)(b * SS + n * BSZ + t0) * HH);
  int wv = tid >> 6, lane = tid & 63;
  int wm = (wv >> 1) * 32, wn = (wv & 1) * 32;
  int fr = lane & 15, kg = lane >> 4;
  f32x4 acc00 = {0,0,0,0}, acc01 = {0,0,0,0}, acc10 = {0,0,0,0}, acc11 = {0,0,0,0};

  for (int k0 = 0; k0 < HH; k0 += 64) {
    #pragma unroll
    for (int i = 0; i < 16; ++i) {
      int e = i * 256 + tid; int r = e >> 6, c = e & 63;
      xs_bf[r][c] = f2bf(xb[(size_t)r * HH + k0 + c]);
    }
    #pragma unroll
    for (int i = 0; i < 16; ++i) {
      int e = i * 256 + tid; int r = e >> 6, c = e & 63;
      wsT[c][r] = f2bf(tw1[(size_t)(k0 + r) * HHALF + j0 + c]);
    }
    __syncthreads();
    #pragma unroll
    for (int kc = 0; kc < 64; kc += 32) {
      int ks = kc + kg * 8;
      bf16x8 a0 = *(const bf16x8*)&xs_bf[wm + fr][ks];
      bf16x8 a1 = *(const bf16x8*)&xs_bf[wm + 16 + fr][ks];
      bf16x8 b0 = *(const bf16x8*)&wsT[wn + fr][ks];
      bf16x8 b1 = *(const bf16x8*)&wsT[wn + 16 + fr][ks];
      acc00 = __builtin_amdgcn_mfma_f32_16x16x32_bf16(a0, b0, acc00, 0, 0, 0);
      acc01 = __builtin_amdgcn_mfma_f32_16x16x32_bf16(a0, b1, acc01, 0, 0, 0);
      acc10 = __builtin_amdgcn_mfma_f32_16x16x32_bf16(a1, b0, acc10, 0, 0, 0);
      acc11 = __builtin_amdgcn_mfma_f32_16x16x32_bf16(a1, b1, acc11, 0, 0, 0);
    }
    __syncthreads();
  }
  #pragma unroll
  for (int r = 0; r < 4; ++r) {
    int row0 = wm + kg * 4 + r, row1 = wm + 16 + kg * 4 + r;
    int col0 = wn + fr,         col1 = wn + 16 + fr;
    float v00 = acc00[r] + tb1[j0 + col0];
    float v01 = acc01[r] + tb1[j0 + col1];
    float v10 = acc10[r] + tb1[j0 + col0];
    float v11 = acc11[r] + tb1[j0 + col1];
    ths[row0][col0] = 0.5f * v00 * (1.0f + erff(v00 * 0.70710678f));
    ths[row0][col1] = 0.5f * v01 * (1.0f + erff(v01 * 0.70710678f));
    ths[row1][col0] = 0.5f * v10 * (1.0f + erff(v10 * 0.70710678f));
    ths[row1][col1] = 0.5f * v11 * (1.0f + erff(v11 * 0.70710678f));
  }
  __syncthreads();
  float* lp = lpart + (size_t)nc * (BSZ * EE);
  #pragma unroll
  for (int l = 0; l < 4; ++l) {
    int idx = l * 256 + tid; int t = idx >> 4, e = idx & 15;
    float s = 0;
    #pragma unroll
    for (int jj = 0; jj < 64; ++jj) s += ths[t][jj] * tw2[(size_t)(j0 + jj) * EE + e];
    lp[(t0 + t) * EE + e] = s;
  }
}

// ---------------- K5: token softmax + routing write + aux KL (merged tail) ----------------
__global__ __launch_bounds__(1024) void k_tail(const double* __restrict__ ent,
    const float* __restrict__ lpart, const float* __restrict__ tb2,
    const float* __restrict__ bwv, const int* __restrict__ bwi,
    float* __restrict__ routing, float* __restrict__ outaux) {
  __shared__ int flg_s[NB + 1];
  __shared__ double up[16][EE];
  __shared__ double us[EE];
  int tid = threadIdx.x;
  if (tid < 64) {
    int f, fb;
    wave_flags(ent, tid, f, fb);
    if (tid < NB) flg_s[tid] = f;
    if (tid == 0) flg_s[NB] = fb;
  }
  __syncthreads();
  int fb = flg_s[NB];
  if (fb >= 0) {
    int b = fb >> 3, n = fb & 7;
    int t = tid;                      // 1024 threads = 1024 tokens
    float l[EE];
    #pragma unroll
    for (int e = 0; e < EE; ++e) {
      float s = tb2[e];
      #pragma unroll
      for (int nc = 0; nc < 16; ++nc) s += lpart[(size_t)nc * (BSZ * EE) + t * EE + e];
      l[e] = s;
    }
    float mx = l[0];
    for (int e = 1; e < EE; ++e) mx = fmaxf(mx, l[e]);
    float se = 0;
    for (int e = 0; e < EE; ++e) { l[e] = expf(l[e] - mx); se += l[e]; }
    float inv = 1.0f / se;
    for (int e = 0; e < EE; ++e) l[e] *= inv;
    float4* orow = (float4*)(routing + ((size_t)(b * SS + n * BSZ + t) * EE));
    orow[0] = make_float4(l[0], l[1], l[2], l[3]);
    orow[1] = make_float4(l[4], l[5], l[6], l[7]);
    orow[2] = make_float4(l[8], l[9], l[10], l[11]);
    orow[3] = make_float4(l[12], l[13], l[14], l[15]);
    int w = tid >> 6;
    for (int e = 0; e < EE; ++e) {
      double v = (double)l[e];
      for (int o = 32; o; o >>= 1) v += __shfl_down(v, o);
      if ((tid & 63) == 0) up[w][e] = v;
    }
  }
  __syncthreads();
  if (tid < EE) {
    double s = 0;
    if (fb >= 0) for (int w = 0; w < 16; ++w) s += up[w][tid];
    for (int i = 0; i < NB; ++i)
      if (flg_s[i] == 2 && bwi[i] == tid) s += (double)BSZ * (double)bwv[i];
    us[tid] = s;
  }
  __syncthreads();
  if (tid == 0) {
    double aux = 0;
    const double target = 1.0 / EE;
    for (int e = 0; e < EE; ++e) {
      double u = us[e] / (double)(BB * SS);
      aux += target * log(target / (u + 1e-10));
    }
    *outaux = (float)aux;
  }
}

extern "C" void kernel_launch(void* const* d_in, const int* in_sizes, int n_in,
                              void* d_out, int out_size, void* d_ws, size_t ws_size,
                              hipStream_t stream) {
  const float* x   = (const float*)d_in[0];
  const float* bw1 = (const float*)d_in[1];
  const float* bb1 = (const float*)d_in[2];
  const float* lng = (const float*)d_in[3];
  const float* lnb = (const float*)d_in[4];
  const float* bw2 = (const float*)d_in[5];
  const float* bb2 = (const float*)d_in[6];
  const float* tw1 = (const float*)d_in[7];
  const float* tb1 = (const float*)d_in[8];
  const float* tw2 = (const float*)d_in[9];
  const float* tb2 = (const float*)d_in[10];
  float* routing = (float*)d_out;
  float* outaux = routing + (size_t)BB * SS * EE;

  char* w = (char*)d_ws;
  size_t off = 0;
  double* part  = (double*)(w + off); off += (size_t)NB * TC * HH * 8;    // 8 MB
  double* g1p   = (double*)(w + off); off += (size_t)KSP * NB * BRD_ * 8; // 4 MB
  float*  lpart = (float*) (w + off); off += 16 * (size_t)BSZ * EE * 4;   // 1 MB
  double* ent   = (double*)(w + off); off += NB * 8;
  float*  bwv   = (float*) (w + off); off += 256;
  int*    bwi   = (int*)   (w + off); off += 256;

  hipLaunchKernelGGL(k_bmean,   dim3(NB * TC), dim3(256),  0, stream, x, part);
  hipLaunchKernelGGL(k_g1,      dim3(256),     dim3(256),  0, stream, part, bw1, g1p);
  hipLaunchKernelGGL(k_router2, dim3(NB),      dim3(256),  0, stream, g1p,
                     bb1, lng, lnb, bw2, bb2, ent, bwv, bwi);
  hipLaunchKernelGGL(k_out,     dim3(512),     dim3(256),  0, stream, ent, bwv, bwi,
                     x, tw1, tb1, tw2, routing, lpart);
  hipLaunchKernelGGL(k_tail,    dim3(1),       dim3(1024), 0, stream, ent, lpart, tb2,
                     bwv, bwi, routing, outaux);
}

// Round 9
// 76.781 us; speedup vs baseline: 2.8802x; 1.3299x over previous
//
#include <hip/hip_runtime.h>
#include <math.h>

#define BB 4
#define SS 8192
#define HH 2048
#define EE 16
#define BRD_ 256
#define BSZ 1024   /* block size from _adjust(8192) */
#define NN 8       /* SS/BSZ */
#define NB 32      /* BB*NN */
#define MAXTOK 1720 /* int(8192*0.21000000000000002) */
#define HHALF 1024
#define TC 16      /* t-chunks per block for the mean kernel */
#define ROWS 64    /* BSZ / TC */
#define KSP 32     /* k-slices for GEMM1 */
#define KL 64      /* HH / KSP */
#define JL 64      /* j-slice width */

typedef __attribute__((ext_vector_type(8))) short bf16x8;
typedef __attribute__((ext_vector_type(4))) float f32x4;
typedef __attribute__((ext_vector_type(4))) float f32x4v;

__device__ inline short f2bf(float f) {
  unsigned u = __builtin_bit_cast(unsigned, f);
  u += 0x7FFFu + ((u >> 16) & 1u);   // RNE
  return (short)(u >> 16);
}

// ---- inline wave-parallel flag logic (lanes 0..63 of one wave; NB=32, KBUD=1) ----
__device__ inline void wave_flags(const double* __restrict__ ent, int l,
                                  int& flag_out, int& fb_out) {
  const double THR = 0.6 * 1.1;  // 0.66000000000000003
  double e = (l < NB) ? ent[l] : -INFINITY;
  bool m1 = (l < NB) && (e > THR);
  unsigned long long m1mask = __ballot(m1);
  int th = __popcll(m1mask);
  double sel = m1 ? e : -INFINITY;
  #pragma unroll
  for (int o = 32; o; o >>= 1) sel = fmax(sel, __shfl_xor(sel, o));
  // cond = (th*1024>1720)&&(th>0)&&(1<th) <=> th>=2 ; kth = max of selected (KBUD=1)
  bool m2 = (th >= 2) ? ((l < NB) && (e > sel)) : m1;
  unsigned long long m2mask = __ballot(m2);
  int cum = __popcll(m2mask & ((2ULL << l) - 1ULL)) * BSZ;  // inclusive prefix
  bool tf = m2 && (cum <= MAXTOK);
  bool bf = (l < NB) && ((!m1) || (m2 && !tf));
  flag_out = tf ? 1 : (bf ? 2 : 0);
  unsigned long long tfmask = __ballot(tf);
  fb_out = tfmask ? (__ffsll(tfmask) - 1) : -1;
}

// ---------------- K1: block mean partial sums (memory-bound floor) ----------------
__global__ __launch_bounds__(256) void k_bmean(const float* __restrict__ x,
                                               double* __restrict__ part) {
  int wg = blockIdx.x;          // NB*TC = 512 wgs
  int bn = wg >> 4, tc = wg & 15;
  int b = bn >> 3, n = bn & 7;
  int tid = threadIdx.x;
  const float* base = x + ((size_t)(b * SS + n * BSZ + tc * ROWS) * HH);
  double a0=0,a1=0,a2=0,a3=0,a4=0,a5=0,a6=0,a7=0;
  #pragma unroll 4
  for (int t = 0; t < ROWS; ++t) {
    const f32x4v* r = (const f32x4v*)(base + (size_t)t * HH);
    f32x4v u = __builtin_nontemporal_load(r + tid);        // h = tid*4 .. +3
    f32x4v v = __builtin_nontemporal_load(r + tid + 256);  // h = 1024 + tid*4 .. +3
    a0 += u.x; a1 += u.y; a2 += u.z; a3 += u.w;
    a4 += v.x; a5 += v.y; a6 += v.z; a7 += v.w;
  }
  double* p = part + ((size_t)bn * TC + tc) * HH;
  int hA = tid * 4, hB = 1024 + tid * 4;
  p[hA] = a0; p[hA+1] = a1; p[hA+2] = a2; p[hA+3] = a3;
  p[hB] = a4; p[hB+1] = a5; p[hB+2] = a6; p[hB+3] = a7;
}

// ---------------- K2: reduce+GEMM1, 128 wgs = 32 k-slices x 4 j-slices ----------------
__global__ __launch_bounds__(256) void k_g1(const double* __restrict__ part,
    const float* __restrict__ bw1, double* __restrict__ g1part) {
  __shared__ double brs[NB][KL];  // 16 KB block means, this k-slice
  __shared__ float  wsm[KL][JL];  // 16 KB bw1 slice
  int bid = blockIdx.x;
  int kq = bid >> 2, jt = bid & 3;
  int k0 = kq * KL, j0 = jt * JL;
  int tid = threadIdx.x;
  #pragma unroll
  for (int i = 0; i < 8; ++i) {
    int e = i * 256 + tid;
    int bn = e >> 6, k = e & 63;
    const double* pp = part + ((size_t)bn * TC) * HH + k0 + k;
    double s = 0;
    #pragma unroll
    for (int tc = 0; tc < TC; ++tc) s += pp[(size_t)tc * HH];
    brs[bn][k] = s * (1.0 / BSZ);
  }
  #pragma unroll
  for (int i = 0; i < 4; ++i) {
    int f = i * 256 + tid;
    int r = f >> 4, c4 = f & 15;
    float4 v = *(const float4*)(bw1 + (size_t)(k0 + r) * BRD_ + j0 + c4 * 4);
    *(float4*)&wsm[r][c4 * 4] = v;
  }
  __syncthreads();
  int j = tid & 63;
  int bh = (tid >> 6) * 8;
  double acc[8];
  #pragma unroll
  for (int r = 0; r < 8; ++r) acc[r] = 0;
  #pragma unroll 8
  for (int k = 0; k < KL; ++k) {
    double wv = (double)wsm[k][j];
    #pragma unroll
    for (int r = 0; r < 8; ++r) acc[r] += brs[bh + r][k] * wv;
  }
  #pragma unroll
  for (int r = 0; r < 8; ++r)
    g1part[((size_t)kq * NB + bh + r) * BRD_ + j0 + j] = acc[r];
}

// ---------------- K3: per-block LN -> GELU -> GEMM2 -> softmax/entropy/argmax ----------------
__global__ __launch_bounds__(256) void k_router2(const double* __restrict__ g1part,
    const float* __restrict__ bb1, const float* __restrict__ lng, const float* __restrict__ lnb,
    const float* __restrict__ bw2, const float* __restrict__ bb2,
    double* __restrict__ ent, float* __restrict__ bwv, int* __restrict__ bwi) {
  __shared__ double tg[BRD_];
  __shared__ double p3[16][EE];
  __shared__ double red[4];
  __shared__ double l2[EE];
  __shared__ double bcast;
  int bn = blockIdx.x, tid = threadIdx.x;

  double a = (double)bb1[tid];
  #pragma unroll
  for (int kq = 0; kq < KSP; ++kq) a += g1part[((size_t)kq * NB + bn) * BRD_ + tid];

  double v = a;
  for (int o = 32; o; o >>= 1) v += __shfl_down(v, o);
  if ((tid & 63) == 0) red[tid >> 6] = v;
  __syncthreads();
  if (tid == 0) bcast = (red[0] + red[1] + red[2] + red[3]) * (1.0 / BRD_);
  __syncthreads();
  double m = bcast;
  double d = a - m;
  v = d * d;
  for (int o = 32; o; o >>= 1) v += __shfl_down(v, o);
  if ((tid & 63) == 0) red[tid >> 6] = v;
  __syncthreads();
  if (tid == 0) bcast = (red[0] + red[1] + red[2] + red[3]) * (1.0 / BRD_);
  __syncthreads();
  double var = bcast;
  double xn = d / sqrt(var + 1e-5) * (double)lng[tid] + (double)lnb[tid];
  tg[tid] = 0.5 * xn * (1.0 + erf(xn * 0.7071067811865476));  // exact GELU
  __syncthreads();

  {
    int e = tid & 15, jc = tid >> 4;
    double s = 0;
    const float* w2 = bw2 + (size_t)(jc * 16) * EE + e;
    #pragma unroll
    for (int jj = 0; jj < 16; ++jj) s += tg[jc * 16 + jj] * (double)w2[jj * EE];
    p3[jc][e] = s;
  }
  __syncthreads();
  if (tid < EE) {
    double acc = (double)bb2[tid];
    #pragma unroll
    for (int jc = 0; jc < 16; ++jc) acc += p3[jc][tid];
    l2[tid] = acc;
  }
  __syncthreads();

  if (tid < 64) {
    int e = tid & 15;
    double le = l2[e];
    double mx = le;
    #pragma unroll
    for (int o = 1; o < 16; o <<= 1) mx = fmax(mx, __shfl_xor(mx, o));
    double pe = exp(le - mx);
    double se = pe;
    #pragma unroll
    for (int o = 1; o < 16; o <<= 1) se += __shfl_xor(se, o);
    double pr = pe / se;
    double q = pr + 1e-10;
    double term = -q * log(q);
    double es = term;
    #pragma unroll
    for (int o = 1; o < 16; o <<= 1) es += __shfl_xor(es, o);
    double mp = pr;
    #pragma unroll
    for (int o = 1; o < 16; o <<= 1) mp = fmax(mp, __shfl_xor(mp, o));
    unsigned long long eqm = __ballot((tid < 16) && (pr == mp));
    if (tid == 0) {
      ent[bn] = es / log(16.0);
      bwv[bn] = (float)mp;
      bwi[bn] = __ffsll(eqm) - 1;
    }
  }
}

// ---------------- K4: merged fill + MFMA token-GEMM (512 wgs; flags inline) ----------------
__global__ __launch_bounds__(256) void k_out(const double* __restrict__ ent,
    const float* __restrict__ bwv, const int* __restrict__ bwi,
    const float* __restrict__ x, const float* __restrict__ tw1, const float* __restrict__ tb1,
    const float* __restrict__ tw2, float* __restrict__ routing, float* __restrict__ lpart) {
  __shared__ int flg_s[NB + 1];
  __shared__ short xs_bf[64][72];   // stride 144B (2-way free)
  __shared__ short wsT[64][72];     // transposed tw1 slice: wsT[col][k]
  __shared__ float ths[64][65];     // gelu output
  int tid = threadIdx.x;
  int bid = blockIdx.x;
  if (tid < 64) {
    int f, fb;
    wave_flags(ent, tid, f, fb);
    if (tid < NB) flg_s[tid] = f;
    if (tid == 0) flg_s[NB] = fb;
  }
  __syncthreads();

  if (bid < 256) {   // ---- fill path: wg = (bn, seg) ----
    int bn = bid >> 3, seg = bid & 7;
    int fl = flg_s[bn];
    if (fl == 1) return;  // token path writes these rows
    int b = bn >> 3, n = bn & 7;
    f32x4v z = {0.f, 0.f, 0.f, 0.f};
    f32x4v val = z;
    int c_hit = -1;
    if (fl == 2) {
      int ai = bwi[bn];
      c_hit = ai >> 2;
      val[ai & 3] = bwv[bn];
    }
    f32x4v* out = (f32x4v*)(routing + ((size_t)(b * SS + n * BSZ + seg * 128) * EE));
    #pragma unroll
    for (int l = 0; l < 2; ++l) {
      int idx = l * 256 + tid;
      int c = idx & 3;
      __builtin_nontemporal_store((c == c_hit) ? val : z, out + idx);
    }
    return;
  }

  // ---- token GEMM path (bf16 MFMA): wg = (tg, nc): 64 tokens x 64 cols, K=2048 ----
  int fb = flg_s[NB];
  if (fb < 0) return;
  int b = fb >> 3, n = fb & 7;
  int tb = bid - 256;
  int tg = tb >> 4, nc = tb & 15;
  int t0 = tg * 64, j0 = nc * 64;
  const float* xb = x + ((size_t)(b * SS + n * BSZ + t0) * HH);
  int wv = tid >> 6, lane = tid & 63;
  int wm = (wv >> 1) * 32, wn = (wv & 1) * 32;
  int fr = lane & 15, kg = lane >> 4;
  f32x4 acc00 = {0,0,0,0}, acc01 = {0,0,0,0}, acc10 = {0,0,0,0}, acc11 = {0,0,0,0};

  for (int k0 = 0; k0 < HH; k0 += 64) {
    #pragma unroll
    for (int i = 0; i < 16; ++i) {
      int e = i * 256 + tid; int r = e >> 6, c = e & 63;
      xs_bf[r][c] = f2bf(xb[(size_t)r * HH + k0 + c]);
    }
    #pragma unroll
    for (int i = 0; i < 16; ++i) {
      int e = i * 256 + tid; int r = e >> 6, c = e & 63;
      wsT[c][r] = f2bf(tw1[(size_t)(k0 + r) * HHALF + j0 + c]);
    }
    __syncthreads();
    #pragma unroll
    for (int kc = 0; kc < 64; kc += 32) {
      int ks = kc + kg * 8;
      bf16x8 a0 = *(const bf16x8*)&xs_bf[wm + fr][ks];
      bf16x8 a1 = *(const bf16x8*)&xs_bf[wm + 16 + fr][ks];
      bf16x8 b0 = *(const bf16x8*)&wsT[wn + fr][ks];
      bf16x8 b1 = *(const bf16x8*)&wsT[wn + 16 + fr][ks];
      acc00 = __builtin_amdgcn_mfma_f32_16x16x32_bf16(a0, b0, acc00, 0, 0, 0);
      acc01 = __builtin_amdgcn_mfma_f32_16x16x32_bf16(a0, b1, acc01, 0, 0, 0);
      acc10 = __builtin_amdgcn_mfma_f32_16x16x32_bf16(a1, b0, acc10, 0, 0, 0);
      acc11 = __builtin_amdgcn_mfma_f32_16x16x32_bf16(a1, b1, acc11, 0, 0, 0);
    }
    __syncthreads();
  }
  #pragma unroll
  for (int r = 0; r < 4; ++r) {
    int row0 = wm + kg * 4 + r, row1 = wm + 16 + kg * 4 + r;
    int col0 = wn + fr,         col1 = wn + 16 + fr;
    float v00 = acc00[r] + tb1[j0 + col0];
    float v01 = acc01[r] + tb1[j0 + col1];
    float v10 = acc10[r] + tb1[j0 + col0];
    float v11 = acc11[r] + tb1[j0 + col1];
    ths[row0][col0] = 0.5f * v00 * (1.0f + erff(v00 * 0.70710678f));
    ths[row0][col1] = 0.5f * v01 * (1.0f + erff(v01 * 0.70710678f));
    ths[row1][col0] = 0.5f * v10 * (1.0f + erff(v10 * 0.70710678f));
    ths[row1][col1] = 0.5f * v11 * (1.0f + erff(v11 * 0.70710678f));
  }
  __syncthreads();
  float* lp = lpart + (size_t)nc * (BSZ * EE);
  #pragma unroll
  for (int l = 0; l < 4; ++l) {
    int idx = l * 256 + tid; int t = idx >> 4, e = idx & 15;
    float s = 0;
    #pragma unroll
    for (int jj = 0; jj < 64; ++jj) s += ths[t][jj] * tw2[(size_t)(j0 + jj) * EE + e];
    lp[(t0 + t) * EE + e] = s;
  }
}

// ---------------- K5: token softmax + routing write + aux KL (merged tail) ----------------
__global__ __launch_bounds__(1024) void k_tail(const double* __restrict__ ent,
    const float* __restrict__ lpart, const float* __restrict__ tb2,
    const float* __restrict__ bwv, const int* __restrict__ bwi,
    float* __restrict__ routing, float* __restrict__ outaux) {
  __shared__ int flg_s[NB + 1];
  __shared__ double up[16][EE];
  __shared__ double us[EE];
  int tid = threadIdx.x;
  if (tid < 64) {
    int f, fb;
    wave_flags(ent, tid, f, fb);
    if (tid < NB) flg_s[tid] = f;
    if (tid == 0) flg_s[NB] = fb;
  }
  __syncthreads();
  int fb = flg_s[NB];
  if (fb >= 0) {
    int b = fb >> 3, n = fb & 7;
    int t = tid;                      // 1024 threads = 1024 tokens
    float l[EE];
    #pragma unroll
    for (int e = 0; e < EE; ++e) {
      float s = tb2[e];
      #pragma unroll
      for (int nc = 0; nc < 16; ++nc) s += lpart[(size_t)nc * (BSZ * EE) + t * EE + e];
      l[e] = s;
    }
    float mx = l[0];
    for (int e = 1; e < EE; ++e) mx = fmaxf(mx, l[e]);
    float se = 0;
    for (int e = 0; e < EE; ++e) { l[e] = expf(l[e] - mx); se += l[e]; }
    float inv = 1.0f / se;
    for (int e = 0; e < EE; ++e) l[e] *= inv;
    float4* orow = (float4*)(routing + ((size_t)(b * SS + n * BSZ + t) * EE));
    orow[0] = make_float4(l[0], l[1], l[2], l[3]);
    orow[1] = make_float4(l[4], l[5], l[6], l[7]);
    orow[2] = make_float4(l[8], l[9], l[10], l[11]);
    orow[3] = make_float4(l[12], l[13], l[14], l[15]);
    int w = tid >> 6;
    for (int e = 0; e < EE; ++e) {
      double v = (double)l[e];
      for (int o = 32; o; o >>= 1) v += __shfl_down(v, o);
      if ((tid & 63) == 0) up[w][e] = v;
    }
  }
  __syncthreads();
  if (tid < EE) {
    double s = 0;
    if (fb >= 0) for (int w = 0; w < 16; ++w) s += up[w][tid];
    for (int i = 0; i < NB; ++i)
      if (flg_s[i] == 2 && bwi[i] == tid) s += (double)BSZ * (double)bwv[i];
    us[tid] = s;
  }
  __syncthreads();
  if (tid == 0) {
    double aux = 0;
    const double target = 1.0 / EE;
    for (int e = 0; e < EE; ++e) {
      double u = us[e] / (double)(BB * SS);
      aux += target * log(target / (u + 1e-10));
    }
    *outaux = (float)aux;
  }
}

extern "C" void kernel_launch(void* const* d_in, const int* in_sizes, int n_in,
                              void* d_out, int out_size, void* d_ws, size_t ws_size,
                              hipStream_t stream) {
  const float* x   = (const float*)d_in[0];
  const float* bw1 = (const float*)d_in[1];
  const float* bb1 = (const float*)d_in[2];
  const float* lng = (const float*)d_in[3];
  const float* lnb = (const float*)d_in[4];
  const float* bw2 = (const float*)d_in[5];
  const float* bb2 = (const float*)d_in[6];
  const float* tw1 = (const float*)d_in[7];
  const float* tb1 = (const float*)d_in[8];
  const float* tw2 = (const float*)d_in[9];
  const float* tb2 = (const float*)d_in[10];
  float* routing = (float*)d_out;
  float* outaux = routing + (size_t)BB * SS * EE;

  char* w = (char*)d_ws;
  size_t off = 0;
  double* part  = (double*)(w + off); off += (size_t)NB * TC * HH * 8;    // 8 MB
  double* g1p   = (double*)(w + off); off += (size_t)KSP * NB * BRD_ * 8; // 2 MB
  float*  lpart = (float*) (w + off); off += 16 * (size_t)BSZ * EE * 4;   // 1 MB
  double* ent   = (double*)(w + off); off += NB * 8;
  float*  bwv   = (float*) (w + off); off += 256;
  int*    bwi   = (int*)   (w + off); off += 256;

  hipLaunchKernelGGL(k_bmean,   dim3(NB * TC), dim3(256),  0, stream, x, part);
  hipLaunchKernelGGL(k_g1,      dim3(128),     dim3(256),  0, stream, part, bw1, g1p);
  hipLaunchKernelGGL(k_router2, dim3(NB),      dim3(256),  0, stream, g1p,
                     bb1, lng, lnb, bw2, bb2, ent, bwv, bwi);
  hipLaunchKernelGGL(k_out,     dim3(512),     dim3(256),  0, stream, ent, bwv, bwi,
                     x, tw1, tb1, tw2, routing, lpart);
  hipLaunchKernelGGL(k_tail,    dim3(1),       dim3(1024), 0, stream, ent, lpart, tb2,
                     bwv, bwi, routing, outaux);
}

// Round 10
// 62.088 us; speedup vs baseline: 3.5619x; 1.2367x over previous
//
#include <hip/hip_runtime.h>
#include <math.h>

#define BB 4
#define SS 8192
#define HH 2048
#define EE 16
#define BRD_ 256
#define BSZ 1024   /* block size from _adjust(8192) */
#define NN 8       /* SS/BSZ */
#define NB 32      /* BB*NN */
#define MAXTOK 1720 /* int(8192*0.21000000000000002) */
#define HHALF 1024
#define HSLC 16    /* h-slices: 2048/128 */
#define HSW 128    /* h-slice width */

typedef __attribute__((ext_vector_type(8))) short bf16x8;
typedef __attribute__((ext_vector_type(4))) float f32x4;
typedef __attribute__((ext_vector_type(4))) float f32x4v;

__device__ inline short f2bf(float f) {
  unsigned u = __builtin_bit_cast(unsigned, f);
  u += 0x7FFFu + ((u >> 16) & 1u);   // RNE
  return (short)(u >> 16);
}

// ---- inline wave-parallel flag logic (lanes 0..63 of one wave; NB=32, KBUD=1) ----
__device__ inline void wave_flags(const double* __restrict__ ent, int l,
                                  int& flag_out, int& fb_out) {
  const double THR = 0.6 * 1.1;  // 0.66000000000000003
  double e = (l < NB) ? ent[l] : -INFINITY;
  bool m1 = (l < NB) && (e > THR);
  unsigned long long m1mask = __ballot(m1);
  int th = __popcll(m1mask);
  double sel = m1 ? e : -INFINITY;
  #pragma unroll
  for (int o = 32; o; o >>= 1) sel = fmax(sel, __shfl_xor(sel, o));
  // cond = (th*1024>1720)&&(th>0)&&(1<th) <=> th>=2 ; kth = max of selected (KBUD=1)
  bool m2 = (th >= 2) ? ((l < NB) && (e > sel)) : m1;
  unsigned long long m2mask = __ballot(m2);
  int cum = __popcll(m2mask & ((2ULL << l) - 1ULL)) * BSZ;  // inclusive prefix
  bool tf = m2 && (cum <= MAXTOK);
  bool bf = (l < NB) && ((!m1) || (m2 && !tf));
  flag_out = tf ? 1 : (bf ? 2 : 0);
  unsigned long long tfmask = __ballot(tf);
  fb_out = tfmask ? (__ffsll(tfmask) - 1) : -1;
}

// ========== K1: fused column-sliced block-mean + GEMM1 k-slice (512 wgs) ==========
// wg = (bn, hc). Phase A: mean of x[bn-rows, hc*128..+127] (fp64).
// Phase B (linearity): partial GEMM1 contribution of this k-slice into g1p[hc][bn][:].
__global__ __launch_bounds__(256) void k_meang1(const float* __restrict__ x,
    const float* __restrict__ bw1, double* __restrict__ g1p) {
  __shared__ double mq[4][HSW];   // 4 KB row-quarter col sums
  __shared__ double mean[HSW];
  int wg = blockIdx.x;
  int bn = wg >> 4, hc = wg & 15;
  int b = bn >> 3, n = bn & 7;
  int tid = threadIdx.x;
  int rq = tid >> 6, lane = tid & 63;   // row-quarter, float2-col

  // Phase A: 256 rows per thread, float2 per row (cols 2*lane, 2*lane+1 of slice)
  const float2* p = (const float2*)(x + ((size_t)(b * SS + n * BSZ + rq * 256) * HH) + hc * HSW);
  double a0 = 0, a1 = 0, a2 = 0, a3 = 0;
  #pragma unroll 8
  for (int rr = 0; rr < 256; rr += 2) {
    float2 v0 = p[(size_t)rr * 1024 + lane];
    float2 v1 = p[(size_t)(rr + 1) * 1024 + lane];
    a0 += v0.x; a1 += v0.y;
    a2 += v1.x; a3 += v1.y;
  }
  mq[rq][lane * 2]     = a0 + a2;
  mq[rq][lane * 2 + 1] = a1 + a3;
  __syncthreads();
  if (tid < HSW)
    mean[tid] = (mq[0][tid] + mq[1][tid] + mq[2][tid] + mq[3][tid]) * (1.0 / BSZ);
  __syncthreads();

  // Phase B: thread j contracts 128-k slice against bw1 column j
  int j = tid;
  const float* wp = bw1 + (size_t)(hc * HSW) * BRD_ + j;
  double c0 = 0, c1 = 0, c2 = 0, c3 = 0;
  #pragma unroll 16
  for (int k = 0; k < HSW; k += 4) {
    c0 += mean[k]     * (double)wp[(size_t)k * BRD_];
    c1 += mean[k + 1] * (double)wp[(size_t)(k + 1) * BRD_];
    c2 += mean[k + 2] * (double)wp[(size_t)(k + 2) * BRD_];
    c3 += mean[k + 3] * (double)wp[(size_t)(k + 3) * BRD_];
  }
  g1p[((size_t)hc * NB + bn) * BRD_ + j] = (c0 + c1) + (c2 + c3);
}

// ---------------- K2: per-block LN -> GELU -> GEMM2 -> softmax/entropy/argmax ----------------
__global__ __launch_bounds__(256) void k_router2(const double* __restrict__ g1part,
    const float* __restrict__ bb1, const float* __restrict__ lng, const float* __restrict__ lnb,
    const float* __restrict__ bw2, const float* __restrict__ bb2,
    double* __restrict__ ent, float* __restrict__ bwv, int* __restrict__ bwi) {
  __shared__ double tg[BRD_];
  __shared__ double p3[16][EE];
  __shared__ double red[4];
  __shared__ double l2[EE];
  __shared__ double bcast;
  int bn = blockIdx.x, tid = threadIdx.x;

  double a = (double)bb1[tid];
  #pragma unroll
  for (int hc = 0; hc < HSLC; ++hc) a += g1part[((size_t)hc * NB + bn) * BRD_ + tid];

  double v = a;
  for (int o = 32; o; o >>= 1) v += __shfl_down(v, o);
  if ((tid & 63) == 0) red[tid >> 6] = v;
  __syncthreads();
  if (tid == 0) bcast = (red[0] + red[1] + red[2] + red[3]) * (1.0 / BRD_);
  __syncthreads();
  double m = bcast;
  double d = a - m;
  v = d * d;
  for (int o = 32; o; o >>= 1) v += __shfl_down(v, o);
  if ((tid & 63) == 0) red[tid >> 6] = v;
  __syncthreads();
  if (tid == 0) bcast = (red[0] + red[1] + red[2] + red[3]) * (1.0 / BRD_);
  __syncthreads();
  double var = bcast;
  double xn = d / sqrt(var + 1e-5) * (double)lng[tid] + (double)lnb[tid];
  tg[tid] = 0.5 * xn * (1.0 + erf(xn * 0.7071067811865476));  // exact GELU
  __syncthreads();

  {
    int e = tid & 15, jc = tid >> 4;
    double s = 0;
    const float* w2 = bw2 + (size_t)(jc * 16) * EE + e;
    #pragma unroll
    for (int jj = 0; jj < 16; ++jj) s += tg[jc * 16 + jj] * (double)w2[jj * EE];
    p3[jc][e] = s;
  }
  __syncthreads();
  if (tid < EE) {
    double acc = (double)bb2[tid];
    #pragma unroll
    for (int jc = 0; jc < 16; ++jc) acc += p3[jc][tid];
    l2[tid] = acc;
  }
  __syncthreads();

  if (tid < 64) {
    int e = tid & 15;
    double le = l2[e];
    double mx = le;
    #pragma unroll
    for (int o = 1; o < 16; o <<= 1) mx = fmax(mx, __shfl_xor(mx, o));
    double pe = exp(le - mx);
    double se = pe;
    #pragma unroll
    for (int o = 1; o < 16; o <<= 1) se += __shfl_xor(se, o);
    double pr = pe / se;
    double q = pr + 1e-10;
    double term = -q * log(q);
    double es = term;
    #pragma unroll
    for (int o = 1; o < 16; o <<= 1) es += __shfl_xor(es, o);
    double mp = pr;
    #pragma unroll
    for (int o = 1; o < 16; o <<= 1) mp = fmax(mp, __shfl_xor(mp, o));
    unsigned long long eqm = __ballot((tid < 16) && (pr == mp));
    if (tid == 0) {
      ent[bn] = es / log(16.0);
      bwv[bn] = (float)mp;
      bwi[bn] = __ffsll(eqm) - 1;
    }
  }
}

// ---------------- K3: merged fill + MFMA token-GEMM (512 wgs; flags inline) ----------------
__global__ __launch_bounds__(256) void k_out(const double* __restrict__ ent,
    const float* __restrict__ bwv, const int* __restrict__ bwi,
    const float* __restrict__ x, const float* __restrict__ tw1, const float* __restrict__ tb1,
    const float* __restrict__ tw2, float* __restrict__ routing, float* __restrict__ lpart) {
  __shared__ int flg_s[NB + 1];
  __shared__ short xs_bf[64][72];   // stride 144B (2-way free)
  __shared__ short wsT[64][72];     // transposed tw1 slice: wsT[col][k]
  __shared__ float ths[64][65];     // gelu output
  int tid = threadIdx.x;
  int bid = blockIdx.x;
  if (tid < 64) {
    int f, fb;
    wave_flags(ent, tid, f, fb);
    if (tid < NB) flg_s[tid] = f;
    if (tid == 0) flg_s[NB] = fb;
  }
  __syncthreads();

  if (bid < 256) {   // ---- fill path: wg = (bn, seg) ----
    int bn = bid >> 3, seg = bid & 7;
    int fl = flg_s[bn];
    if (fl == 1) return;  // token path writes these rows
    int b = bn >> 3, n = bn & 7;
    f32x4v z = {0.f, 0.f, 0.f, 0.f};
    f32x4v val = z;
    int c_hit = -1;
    if (fl == 2) {
      int ai = bwi[bn];
      c_hit = ai >> 2;
      val[ai & 3] = bwv[bn];
    }
    f32x4v* out = (f32x4v*)(routing + ((size_t)(b * SS + n * BSZ + seg * 128) * EE));
    #pragma unroll
    for (int l = 0; l < 2; ++l) {
      int idx = l * 256 + tid;
      int c = idx & 3;
      __builtin_nontemporal_store((c == c_hit) ? val : z, out + idx);
    }
    return;
  }

  // ---- token GEMM path (bf16 MFMA): wg = (tg, nc): 64 tokens x 64 cols, K=2048 ----
  int fb = flg_s[NB];
  if (fb < 0) return;
  int b = fb >> 3, n = fb & 7;
  int tb = bid - 256;
  int tg = tb >> 4, nc = tb & 15;
  int t0 = tg * 64, j0 = nc * 64;
  const float* xb = x + ((size_t)(b * SS + n * BSZ + t0) * HH);
  int wv = tid >> 6, lane = tid & 63;
  int wm = (wv >> 1) * 32, wn = (wv & 1) * 32;
  int fr = lane & 15, kg = lane >> 4;
  f32x4 acc00 = {0,0,0,0}, acc01 = {0,0,0,0}, acc10 = {0,0,0,0}, acc11 = {0,0,0,0};

  for (int k0 = 0; k0 < HH; k0 += 64) {
    #pragma unroll
    for (int i = 0; i < 16; ++i) {
      int e = i * 256 + tid; int r = e >> 6, c = e & 63;
      xs_bf[r][c] = f2bf(xb[(size_t)r * HH + k0 + c]);
    }
    #pragma unroll
    for (int i = 0; i < 16; ++i) {
      int e = i * 256 + tid; int r = e >> 6, c = e & 63;
      wsT[c][r] = f2bf(tw1[(size_t)(k0 + r) * HHALF + j0 + c]);
    }
    __syncthreads();
    #pragma unroll
    for (int kc = 0; kc < 64; kc += 32) {
      int ks = kc + kg * 8;
      bf16x8 a0 = *(const bf16x8*)&xs_bf[wm + fr][ks];
      bf16x8 a1 = *(const bf16x8*)&xs_bf[wm + 16 + fr][ks];
      bf16x8 b0 = *(const bf16x8*)&wsT[wn + fr][ks];
      bf16x8 b1 = *(const bf16x8*)&wsT[wn + 16 + fr][ks];
      acc00 = __builtin_amdgcn_mfma_f32_16x16x32_bf16(a0, b0, acc00, 0, 0, 0);
      acc01 = __builtin_amdgcn_mfma_f32_16x16x32_bf16(a0, b1, acc01, 0, 0, 0);
      acc10 = __builtin_amdgcn_mfma_f32_16x16x32_bf16(a1, b0, acc10, 0, 0, 0);
      acc11 = __builtin_amdgcn_mfma_f32_16x16x32_bf16(a1, b1, acc11, 0, 0, 0);
    }
    __syncthreads();
  }
  #pragma unroll
  for (int r = 0; r < 4; ++r) {
    int row0 = wm + kg * 4 + r, row1 = wm + 16 + kg * 4 + r;
    int col0 = wn + fr,         col1 = wn + 16 + fr;
    float v00 = acc00[r] + tb1[j0 + col0];
    float v01 = acc01[r] + tb1[j0 + col1];
    float v10 = acc10[r] + tb1[j0 + col0];
    float v11 = acc11[r] + tb1[j0 + col1];
    ths[row0][col0] = 0.5f * v00 * (1.0f + erff(v00 * 0.70710678f));
    ths[row0][col1] = 0.5f * v01 * (1.0f + erff(v01 * 0.70710678f));
    ths[row1][col0] = 0.5f * v10 * (1.0f + erff(v10 * 0.70710678f));
    ths[row1][col1] = 0.5f * v11 * (1.0f + erff(v11 * 0.70710678f));
  }
  __syncthreads();
  float* lp = lpart + (size_t)nc * (BSZ * EE);
  #pragma unroll
  for (int l = 0; l < 4; ++l) {
    int idx = l * 256 + tid; int t = idx >> 4, e = idx & 15;
    float s = 0;
    #pragma unroll
    for (int jj = 0; jj < 64; ++jj) s += ths[t][jj] * tw2[(size_t)(j0 + jj) * EE + e];
    lp[(t0 + t) * EE + e] = s;
  }
}

// ---------------- K4: token softmax + routing write + aux KL (merged tail) ----------------
__global__ __launch_bounds__(1024) void k_tail(const double* __restrict__ ent,
    const float* __restrict__ lpart, const float* __restrict__ tb2,
    const float* __restrict__ bwv, const int* __restrict__ bwi,
    float* __restrict__ routing, float* __restrict__ outaux) {
  __shared__ int flg_s[NB + 1];
  __shared__ double up[16][EE];
  __shared__ double us[EE];
  int tid = threadIdx.x;
  if (tid < 64) {
    int f, fb;
    wave_flags(ent, tid, f, fb);
    if (tid < NB) flg_s[tid] = f;
    if (tid == 0) flg_s[NB] = fb;
  }
  __syncthreads();
  int fb = flg_s[NB];
  if (fb >= 0) {
    int b = fb >> 3, n = fb & 7;
    int t = tid;                      // 1024 threads = 1024 tokens
    float l[EE];
    #pragma unroll
    for (int e = 0; e < EE; ++e) {
      float s = tb2[e];
      #pragma unroll
      for (int nc = 0; nc < 16; ++nc) s += lpart[(size_t)nc * (BSZ * EE) + t * EE + e];
      l[e] = s;
    }
    float mx = l[0];
    for (int e = 1; e < EE; ++e) mx = fmaxf(mx, l[e]);
    float se = 0;
    for (int e = 0; e < EE; ++e) { l[e] = expf(l[e] - mx); se += l[e]; }
    float inv = 1.0f / se;
    for (int e = 0; e < EE; ++e) l[e] *= inv;
    float4* orow = (float4*)(routing + ((size_t)(b * SS + n * BSZ + t) * EE));
    orow[0] = make_float4(l[0], l[1], l[2], l[3]);
    orow[1] = make_float4(l[4], l[5], l[6], l[7]);
    orow[2] = make_float4(l[8], l[9], l[10], l[11]);
    orow[3] = make_float4(l[12], l[13], l[14], l[15]);
    int w = tid >> 6;
    for (int e = 0; e < EE; ++e) {
      double v = (double)l[e];
      for (int o = 32; o; o >>= 1) v += __shfl_down(v, o);
      if ((tid & 63) == 0) up[w][e] = v;
    }
  }
  __syncthreads();
  if (tid < EE) {
    double s = 0;
    if (fb >= 0) for (int w = 0; w < 16; ++w) s += up[w][tid];
    for (int i = 0; i < NB; ++i)
      if (flg_s[i] == 2 && bwi[i] == tid) s += (double)BSZ * (double)bwv[i];
    us[tid] = s;
  }
  __syncthreads();
  if (tid == 0) {
    double aux = 0;
    const double target = 1.0 / EE;
    for (int e = 0; e < EE; ++e) {
      double u = us[e] / (double)(BB * SS);
      aux += target * log(target / (u + 1e-10));
    }
    *outaux = (float)aux;
  }
}

extern "C" void kernel_launch(void* const* d_in, const int* in_sizes, int n_in,
                              void* d_out, int out_size, void* d_ws, size_t ws_size,
                              hipStream_t stream) {
  const float* x   = (const float*)d_in[0];
  const float* bw1 = (const float*)d_in[1];
  const float* bb1 = (const float*)d_in[2];
  const float* lng = (const float*)d_in[3];
  const float* lnb = (const float*)d_in[4];
  const float* bw2 = (const float*)d_in[5];
  const float* bb2 = (const float*)d_in[6];
  const float* tw1 = (const float*)d_in[7];
  const float* tb1 = (const float*)d_in[8];
  const float* tw2 = (const float*)d_in[9];
  const float* tb2 = (const float*)d_in[10];
  float* routing = (float*)d_out;
  float* outaux = routing + (size_t)BB * SS * EE;

  char* w = (char*)d_ws;
  size_t off = 0;
  double* g1p   = (double*)(w + off); off += (size_t)HSLC * NB * BRD_ * 8; // 1 MB
  float*  lpart = (float*) (w + off); off += 16 * (size_t)BSZ * EE * 4;    // 1 MB
  double* ent   = (double*)(w + off); off += NB * 8;
  float*  bwv   = (float*) (w + off); off += 256;
  int*    bwi   = (int*)   (w + off); off += 256;

  hipLaunchKernelGGL(k_meang1,  dim3(NB * HSLC), dim3(256),  0, stream, x, bw1, g1p);
  hipLaunchKernelGGL(k_router2, dim3(NB),        dim3(256),  0, stream, g1p,
                     bb1, lng, lnb, bw2, bb2, ent, bwv, bwi);
  hipLaunchKernelGGL(k_out,     dim3(512),       dim3(256),  0, stream, ent, bwv, bwi,
                     x, tw1, tb1, tw2, routing, lpart);
  hipLaunchKernelGGL(k_tail,    dim3(1),         dim3(1024), 0, stream, ent, lpart, tb2,
                     bwv, bwi, routing, outaux);
}